// Round 4
// baseline (170.934 us; speedup 1.0000x reference)
//
#include <hip/hip_runtime.h>
#include <hip/hip_bf16.h>
#include <math.h>

// B=256, N=256, E=512, ITER=10
#define Bb   256
#define Nn   256
#define Ee   512
#define TKF  64             // f32 elements per chunk row (staged in LDS)
#define NCH  (Ee / TKF)     // 8 chunks
#define NITER 10

typedef __attribute__((ext_vector_type(8))) short bf16x8;   // MFMA A/B frag (4 VGPR)
typedef __attribute__((ext_vector_type(4))) float f32x4;    // MFMA C/D frag

typedef __attribute__((address_space(1))) const void glb_cv;
typedef __attribute__((address_space(3))) void lds_v;

static __device__ __forceinline__ unsigned short f2bf(float f) {
    __hip_bfloat16 h = __float2bfloat16(f);     // RNE; compiler packs to v_cvt_pk_bf16_f32
    return __builtin_bit_cast(unsigned short, h);
}

// LDS tile: f32 [256 rows][64 k], linear rows (256 B), double-buffered.
// Swizzle (rule #21, both-sides): the global SOURCE is pre-permuted per 16B
// granule (g16 ^= 2*(row&7)) at staging time, and reads XOR the byte offset
// with (row&7)<<5 (32B granules). Strided per-row b128 fragment reads then
// land <=2-way per bank (free, m136).
static __device__ __forceinline__ bf16x8 ldfrag(const float* tb, int row, int kb) {
    const int byteoff = row * 256 + (((kb * 4) ^ ((row & 7) << 5)));
    const float4* p = reinterpret_cast<const float4*>(
        reinterpret_cast<const char*>(tb) + byteoff);
    const float4 a = p[0];
    const float4 b = p[1];
    bf16x8 r;
    r[0] = f2bf(a.x); r[1] = f2bf(a.y); r[2] = f2bf(a.z); r[3] = f2bf(a.w);
    r[4] = f2bf(b.x); r[5] = f2bf(b.y); r[6] = f2bf(b.z); r[7] = f2bf(b.w);
    return r;
}

// 512 threads = 8 waves (4x2 grid); wave (wr,wc) owns rows [wr*64,+64) x cols
// [wc*128,+128) of C = F F^T.  acc[4][8] f32x4 = 128 accum regs/thread; staging
// has ZERO VGPR footprint (global_load_lds), so the 128-reg arch half of the
// 256-reg budget (2 waves/SIMD) holds frags+addresses without spilling.
__global__ __launch_bounds__(512, 2) void crf_mfma(
    const float* __restrict__ feats,   // [B, N, E]
    const float* __restrict__ logits,  // [B, N, 1]
    const float* __restrict__ W,       // [1, N, N]
    float* __restrict__ out)           // [B, N, 1]
{
    const int b    = blockIdx.x;
    const int t    = threadIdx.x;
    const int wave = t >> 6;           // 0..7
    const int lane = t & 63;
    const int wr   = wave >> 1;        // 0..3 (64-row block)
    const int wc   = wave & 1;         // 0..1 (128-col block)
    const int lo   = lane & 15;        // C/D col = lo; A/B row = lo
    const int hi   = lane >> 4;        // C/D row = hi*4+reg; A/B k-base = hi*8

    __shared__ float tile[2 * Nn * TKF];   // 2 x 64 KB fp32 chunk
    __shared__ float invn[Nn];
    __shared__ float svec[Nn];
    __shared__ float uvec[Nn];
    __shared__ float lgv[Nn];
    __shared__ float part[4][Nn];

    f32x4 acc[4][8];
#pragma unroll
    for (int i = 0; i < 4; ++i)
#pragma unroll
        for (int j = 0; j < 8; ++j) acc[i][j] = (f32x4){0.f, 0.f, 0.f, 0.f};

    const float* Fb = feats + (size_t)b * Nn * Ee;

    // stage chunk ch into tile[buf]: 8 x global_load_lds(16B) per wave, no VGPRs.
    // LDS dest is wave-uniform base + lane*16 (linear); source is per-lane with
    // the inverse swizzle so reads can apply the XOR.
    auto stage = [&](int ch, int buf) {
        float* tbase = tile + buf * (Nn * TKF);
#pragma unroll
        for (int i = 0; i < 8; ++i) {
            const int r0s = wave * 32 + i * 4;          // wave-uniform row group
            const int row = r0s + (lane >> 4);          // per-lane row (4 rows/issue)
            const int g16 = (lane & 15) ^ ((row & 7) << 1);  // source 16B granule
            const float* src = Fb + (size_t)row * Ee + ch * TKF + g16 * 4;
            __builtin_amdgcn_global_load_lds((glb_cv*)src,
                                             (lds_v*)(tbase + r0s * TKF), 16, 0, 0);
        }
    };

    // ================= GEMM: C = F F^T, double-buffered chunks =================
    stage(0, 0);
    if (t < Nn) {
        const float u = logits[(size_t)b * Nn + t];
        uvec[t] = u;
        lgv[t]  = u;
    }
    __syncthreads();   // drains vmcnt(0) -> chunk 0 staged

    for (int ch = 0; ch < NCH; ++ch) {
        const int buf = ch & 1;
        if (ch + 1 < NCH) stage(ch + 1, buf ^ 1);   // issue next chunk first
        const float* tb = tile + buf * (Nn * TKF);
#pragma unroll
        for (int ks = 0; ks < 2; ++ks) {
            const int kb = ks * 32 + hi * 8;        // f32 (== bf16) k index
            bf16x8 af[4];
#pragma unroll
            for (int rb = 0; rb < 4; ++rb)
                af[rb] = ldfrag(tb, wr * 64 + rb * 16 + lo, kb);
#pragma unroll
            for (int cg = 0; cg < 2; ++cg) {        // 2 groups of 4 B-frags: caps
                bf16x8 bfv[4];                      // transient f32 pressure
#pragma unroll
                for (int cq = 0; cq < 4; ++cq)
                    bfv[cq] = ldfrag(tb, wc * 128 + (cg * 4 + cq) * 16 + lo, kb);
#pragma unroll
                for (int rb = 0; rb < 4; ++rb)
#pragma unroll
                    for (int cq = 0; cq < 4; ++cq)
                        acc[rb][cg * 4 + cq] = __builtin_amdgcn_mfma_f32_16x16x32_bf16(
                            af[rb], bfv[cq], acc[rb][cg * 4 + cq], 0, 0, 0);
            }
        }
        __syncthreads();   // drains next-chunk loads + guards buf reuse
    }

    // ================= inverse norms from the diagonal =================
    // diag subtile of row-block d=wr*4+rb lives in wave (wr, wc=wr>>1), cb=(wr&1)*4+rb
    if (wc == (wr >> 1)) {
#pragma unroll
        for (int rb = 0; rb < 4; ++rb) {
            if (hi == (lo >> 2)) {                  // lane holding subtile elem (lo,lo)
                const int cbd = (wr & 1) * 4 + rb;
                const f32x4 a = acc[rb][cbd];
                const int reg = lo & 3;
                const float d = (reg == 0) ? a[0] : (reg == 1) ? a[1]
                              : (reg == 2) ? a[2] : a[3];
                invn[wr * 64 + rb * 16 + lo] = 1.0f / sqrtf(d);
            }
        }
    }
    __syncthreads();

    // ===== P = C * invn_r * invn_c * 0.5*(W[r][c]+W[c][r]), in registers =====
    // W[col][rbase..+4) is one contiguous float4; W[row][col] stays scalar.
#pragma unroll
    for (int rb = 0; rb < 4; ++rb) {
        const int rbase = wr * 64 + rb * 16 + hi * 4;
        const float4 ir4 = *reinterpret_cast<const float4*>(&invn[rbase]);
        const float ir[4] = {ir4.x, ir4.y, ir4.z, ir4.w};
#pragma unroll
        for (int cb = 0; cb < 8; ++cb) {
            const int col = wc * 128 + cb * 16 + lo;
            const float ic = invn[col];
            const float4 wt = *reinterpret_cast<const float4*>(&W[col * Nn + rbase]);
            const float wtr[4] = {wt.x, wt.y, wt.z, wt.w};
#pragma unroll
            for (int r = 0; r < 4; ++r) {
                const float wsym = 0.5f * (W[(rbase + r) * Nn + col] + wtr[r]);
                acc[rb][cb][r] = acc[rb][cb][r] * ir[r] * ic * wsym;
            }
        }
    }

    // ================= 10 mean-field iterations =================
    // P symmetric -> e[col] = sum_row P[row][col]*s[row]: in-lane over 16 rows,
    // butterfly over hi-groups, LDS partials over the 4 wr row-blocks.
    for (int itr = 0; itr < NITER; ++itr) {
        if (t < Nn) {
            const float x = lgv[t];
            svec[t] = 2.f / (1.f + __expf(-x)) - 1.f;
        }
        __syncthreads();

        float ep[8] = {0.f, 0.f, 0.f, 0.f, 0.f, 0.f, 0.f, 0.f};
#pragma unroll
        for (int rb = 0; rb < 4; ++rb) {
            const float4 s4 = *reinterpret_cast<const float4*>(
                &svec[wr * 64 + rb * 16 + hi * 4]);
#pragma unroll
            for (int cb = 0; cb < 8; ++cb)
                ep[cb] += acc[rb][cb][0] * s4.x + acc[rb][cb][1] * s4.y
                        + acc[rb][cb][2] * s4.z + acc[rb][cb][3] * s4.w;
        }
#pragma unroll
        for (int cb = 0; cb < 8; ++cb) {
            ep[cb] += __shfl_xor(ep[cb], 16);
            ep[cb] += __shfl_xor(ep[cb], 32);
        }
        if (lane < 16) {
#pragma unroll
            for (int cb = 0; cb < 8; ++cb)
                part[wr][wc * 128 + cb * 16 + lane] = ep[cb];
        }
        __syncthreads();
        if (t < Nn)
            lgv[t] = uvec[t] + part[0][t] + part[1][t] + part[2][t] + part[3][t];
        // next iteration's svec/part writes are after its own barriers; lgv[t]
        // is read only by the thread that wrote it -> no trailing barrier.
    }

    if (t < Nn) out[(size_t)b * Nn + t] = lgv[t];
}

extern "C" void kernel_launch(void* const* d_in, const int* in_sizes, int n_in,
                              void* d_out, int out_size, void* d_ws, size_t ws_size,
                              hipStream_t stream) {
    const float* feats  = (const float*)d_in[0];
    const float* logits = (const float*)d_in[1];
    const float* W      = (const float*)d_in[2];
    float* out = (float*)d_out;

    crf_mfma<<<dim3(Bb), dim3(512), 0, stream>>>(feats, logits, W, out);
}

// Round 5
// 55.469 us; speedup vs baseline: 3.0816x; 3.0816x over previous
//
#include <hip/hip_runtime.h>
#include <hip/hip_bf16.h>
#include <math.h>

// B=256, N=256, E=512, ITER=10
#define Bb   256
#define Nn   256
#define Ee   512
#define TKF  64             // f32 elements per chunk row (staged in LDS)
#define NCH  (Ee / TKF)     // 8 chunks
#define NITER 10

typedef __attribute__((ext_vector_type(8))) short bf16x8;   // MFMA A/B frag (4 VGPR)
typedef __attribute__((ext_vector_type(4))) float f32x4;    // MFMA C/D frag

typedef __attribute__((address_space(1))) const void glb_cv;
typedef __attribute__((address_space(3))) void lds_v;

static __device__ __forceinline__ unsigned short f2bf(float f) {
    __hip_bfloat16 h = __float2bfloat16(f);     // RNE; compiler packs to v_cvt_pk_bf16_f32
    return __builtin_bit_cast(unsigned short, h);
}

// LDS tile: f32 [256 rows][64 k], 256 B rows, double-buffered.
// Swizzle (rule #21, both-sides): 16B-granule XOR — read byte ^= (row&7)<<4,
// source granule pre-permuted g16 ^= (row&7) at staging. 8 consecutive rows
// land on 8 distinct 16B slots mod 128B -> full 32-bank spread, 2-way residual
// (free, m136).  (Round 4's 32B-granule version only gave 4 positions -> 4-way.)
static __device__ __forceinline__ bf16x8 ldfrag(const float* tb, int row, int kb) {
    const int sw = (row & 7) << 4;
    const char* base = reinterpret_cast<const char*>(tb) + row * 256;
    const float4 a = *reinterpret_cast<const float4*>(base + (((kb * 4) + 0) ^ sw));
    const float4 b = *reinterpret_cast<const float4*>(base + (((kb * 4) + 16) ^ sw));
    bf16x8 r;
    r[0] = f2bf(a.x); r[1] = f2bf(a.y); r[2] = f2bf(a.z); r[3] = f2bf(a.w);
    r[4] = f2bf(b.x); r[5] = f2bf(b.y); r[6] = f2bf(b.z); r[7] = f2bf(b.w);
    return r;
}

// 512 threads = 8 waves (4x2 grid); wave (wr,wc) owns rows [wr*64,+64) x cols
// [wc*128,+128) of C = F F^T.  acc[4][8] f32x4 = 128 accum regs/thread; ALL acc
// indices are compile-time (rule #20 — round 3/4's runtime `cbd` index demoted
// acc to scratch: 395->655 MB HBM writes). Staging has zero VGPR footprint.
__global__ __launch_bounds__(512, 2) void crf_mfma(
    const float* __restrict__ feats,   // [B, N, E]
    const float* __restrict__ logits,  // [B, N, 1]
    const float* __restrict__ W,       // [1, N, N]
    float* __restrict__ out)           // [B, N, 1]
{
    const int b    = blockIdx.x;
    const int t    = threadIdx.x;
    const int wave = t >> 6;           // 0..7
    const int lane = t & 63;
    const int wr   = wave >> 1;        // 0..3 (64-row block)
    const int wc   = wave & 1;         // 0..1 (128-col block)
    const int lo   = lane & 15;        // C/D col = lo; A/B row = lo
    const int hi   = lane >> 4;        // C/D row = hi*4+reg; A/B k-base = hi*8

    __shared__ float tile[2 * Nn * TKF];   // 2 x 64 KB fp32 chunk
    __shared__ float invn[Nn];
    __shared__ float svec[Nn];
    __shared__ float uvec[Nn];
    __shared__ float lgv[Nn];
    __shared__ float part[4][Nn];

    f32x4 acc[4][8];
#pragma unroll
    for (int i = 0; i < 4; ++i)
#pragma unroll
        for (int j = 0; j < 8; ++j) acc[i][j] = (f32x4){0.f, 0.f, 0.f, 0.f};

    const float* Fb = feats + (size_t)b * Nn * Ee;

    // stage chunk ch into tile[buf]: 8 x global_load_lds(16B) per wave, no VGPRs.
    // LDS dest: wave-uniform base + lane*16 (linear). Source: per-lane, with the
    // inverse 16B-granule permutation so reads can apply the XOR.
    auto stage = [&](int ch, int buf) {
        float* tbase = tile + buf * (Nn * TKF);
#pragma unroll
        for (int i = 0; i < 8; ++i) {
            const int r0s = wave * 32 + i * 4;               // wave-uniform row group
            const int row = r0s + (lane >> 4);               // per-lane row (4 rows/issue)
            const int g16 = (lane & 15) ^ (row & 7);         // source 16B granule
            const float* src = Fb + (size_t)row * Ee + ch * TKF + g16 * 4;
            __builtin_amdgcn_global_load_lds((glb_cv*)src,
                                             (lds_v*)(tbase + r0s * TKF), 16, 0, 0);
        }
    };

    // ================= GEMM: C = F F^T, double-buffered chunks =================
    stage(0, 0);
    if (t < Nn) {
        const float u = logits[(size_t)b * Nn + t];
        uvec[t] = u;
        lgv[t]  = u;
    }
    __syncthreads();   // drains vmcnt(0) -> chunk 0 staged

    for (int ch = 0; ch < NCH; ++ch) {
        const int buf = ch & 1;
        if (ch + 1 < NCH) stage(ch + 1, buf ^ 1);   // issue next chunk first
        const float* tb = tile + buf * (Nn * TKF);
#pragma unroll
        for (int ks = 0; ks < 2; ++ks) {
            const int kb = ks * 32 + hi * 8;        // f32 (== bf16) k index
            bf16x8 af[4];
#pragma unroll
            for (int rb = 0; rb < 4; ++rb)
                af[rb] = ldfrag(tb, wr * 64 + rb * 16 + lo, kb);
#pragma unroll
            for (int cg = 0; cg < 2; ++cg) {        // 2 groups of 4 B-frags: caps
                bf16x8 bfv[4];                      // transient arch-reg pressure
#pragma unroll
                for (int cq = 0; cq < 4; ++cq)
                    bfv[cq] = ldfrag(tb, wc * 128 + (cg * 4 + cq) * 16 + lo, kb);
#pragma unroll
                for (int rb = 0; rb < 4; ++rb)
#pragma unroll
                    for (int cq = 0; cq < 4; ++cq)
                        acc[rb][cg * 4 + cq] = __builtin_amdgcn_mfma_f32_16x16x32_bf16(
                            af[rb], bfv[cq], acc[rb][cg * 4 + cq], 0, 0, 0);
            }
        }
        __syncthreads();   // drains next-chunk loads + guards buf reuse
    }

    // ======== inverse norms from the diagonal — compile-time acc indices ========
    // For each compile-time (rb,cb): wave-uniform test "is this my diagonal
    // subtile", then lane-divergent row==col store. acc[rb][cb][r] indices are
    // all compile-time -> acc stays in registers (rule #20).
#pragma unroll
    for (int rb = 0; rb < 4; ++rb) {
        const int rowbase = wr * 64 + rb * 16;
#pragma unroll
        for (int cb = 0; cb < 8; ++cb) {
            const int colbase = wc * 128 + cb * 16;
            if (rowbase == colbase) {              // wave-uniform branch
#pragma unroll
                for (int r = 0; r < 4; ++r) {
                    if (hi * 4 + r == lo)          // lane holds subtile diag elem
                        invn[rowbase + hi * 4 + r] = 1.0f / sqrtf(acc[rb][cb][r]);
                }
            }
        }
    }
    __syncthreads();

    // ===== P = C * invn_r * invn_c * 0.5*(W[r][c]+W[c][r]), in registers =====
#pragma unroll
    for (int rb = 0; rb < 4; ++rb) {
        const int rbase = wr * 64 + rb * 16 + hi * 4;
        const float4 ir4 = *reinterpret_cast<const float4*>(&invn[rbase]);
        const float ir[4] = {ir4.x, ir4.y, ir4.z, ir4.w};
#pragma unroll
        for (int cb = 0; cb < 8; ++cb) {
            const int col = wc * 128 + cb * 16 + lo;
            const float ic = invn[col];
            const float4 wt = *reinterpret_cast<const float4*>(&W[col * Nn + rbase]);
            const float wtr[4] = {wt.x, wt.y, wt.z, wt.w};
#pragma unroll
            for (int r = 0; r < 4; ++r) {
                const float wsym = 0.5f * (W[(rbase + r) * Nn + col] + wtr[r]);
                acc[rb][cb][r] = acc[rb][cb][r] * ir[r] * ic * wsym;
            }
        }
    }

    // ================= 10 mean-field iterations =================
    // P symmetric -> e[col] = sum_row P[row][col]*s[row]: in-lane over 16 rows,
    // butterfly over hi-groups, LDS partials over the 4 wr row-blocks.
    for (int itr = 0; itr < NITER; ++itr) {
        if (t < Nn) {
            const float x = lgv[t];
            svec[t] = 2.f / (1.f + __expf(-x)) - 1.f;
        }
        __syncthreads();

        float ep[8] = {0.f, 0.f, 0.f, 0.f, 0.f, 0.f, 0.f, 0.f};
#pragma unroll
        for (int rb = 0; rb < 4; ++rb) {
            const float4 s4 = *reinterpret_cast<const float4*>(
                &svec[wr * 64 + rb * 16 + hi * 4]);
#pragma unroll
            for (int cb = 0; cb < 8; ++cb)
                ep[cb] += acc[rb][cb][0] * s4.x + acc[rb][cb][1] * s4.y
                        + acc[rb][cb][2] * s4.z + acc[rb][cb][3] * s4.w;
        }
#pragma unroll
        for (int cb = 0; cb < 8; ++cb) {
            ep[cb] += __shfl_xor(ep[cb], 16);
            ep[cb] += __shfl_xor(ep[cb], 32);
        }
        if (lane < 16) {
#pragma unroll
            for (int cb = 0; cb < 8; ++cb)
                part[wr][wc * 128 + cb * 16 + lane] = ep[cb];
        }
        __syncthreads();
        if (t < Nn)
            lgv[t] = uvec[t] + part[0][t] + part[1][t] + part[2][t] + part[3][t];
        // next iteration's svec/part writes are after its own barriers; lgv[t]
        // is read only by the thread that wrote it -> no trailing barrier.
    }

    if (t < Nn) out[(size_t)b * Nn + t] = lgv[t];
}

extern "C" void kernel_launch(void* const* d_in, const int* in_sizes, int n_in,
                              void* d_out, int out_size, void* d_ws, size_t ws_size,
                              hipStream_t stream) {
    const float* feats  = (const float*)d_in[0];
    const float* logits = (const float*)d_in[1];
    const float* W      = (const float*)d_in[2];
    float* out = (float*)d_out;

    crf_mfma<<<dim3(Bb), dim3(512), 0, stream>>>(feats, logits, W, out);
}

// Round 7
// 48.667 us; speedup vs baseline: 3.5123x; 1.1398x over previous
//
#include <hip/hip_runtime.h>
#include <hip/hip_bf16.h>
#include <math.h>

// B=256, N=256, E=512, ITER=10
#define Bb   256
#define Nn   256
#define Ee   512
#define TKF  64             // k-elems per chunk
#define NCH  (Ee / TKF)     // 8 chunks
#define NITER 10

typedef __attribute__((ext_vector_type(8))) short bf16x8;   // MFMA A/B frag (4 VGPR)
typedef __attribute__((ext_vector_type(4))) float f32x4;    // MFMA C/D frag

typedef __attribute__((address_space(1))) const void glb_cv;
typedef __attribute__((address_space(3))) void lds_v;

static __device__ __forceinline__ unsigned short f2bf(float f) {
    __hip_bfloat16 h = __float2bfloat16(f);     // RNE; pairs fuse to v_cvt_pk_bf16_f32
    return __builtin_bit_cast(unsigned short, h);
}

// bf16 tile: [256 rows][64 k], 128 B rows, XOR swizzle byte ^= (row&7)<<4.
// A wave's 64-lane fragment read (rows base+lo, 4 hi-groups at different k)
// lands 8 lanes per 16B slot x 8 slots = full 32-bank coverage = min cycles.
static __device__ __forceinline__ bf16x8 ldfrag(const unsigned char* bt, int row, int ks, int hi) {
    const int byte = row * 128 + (((ks * 64 + hi * 16)) ^ ((row & 7) << 4));
    return *reinterpret_cast<const bf16x8*>(bt + byte);
}

// ---------- Wsym = 0.5*(W + W^T): direct, obviously-correct version ----------
// (Round 6's tiled version launched 64 blocks for a 16-tile problem: OOB W
// reads + OOB wsym writes past ws_size corrupted memory -> absmax 1.77.)
// 64 blocks x 256 threads x 4 elems = 65536 = N*N. Gathered column reads are
// L2-resident (W = 256 KB); whole kernel is ~2-3 us, runs once per launch.
__global__ __launch_bounds__(256) void wsym_k(const float* __restrict__ W,
                                              float* __restrict__ wsym) {
    const int idx = blockIdx.x * 256 + threadIdx.x;   // 0..16383
    const int r  = idx >> 6;                          // row 0..255
    const int c0 = (idx & 63) * 4;                    // col group
    const float4 a = *reinterpret_cast<const float4*>(&W[r * Nn + c0]);
    float4 o;
    o.x = 0.5f * (a.x + W[(c0 + 0) * Nn + r]);
    o.y = 0.5f * (a.y + W[(c0 + 1) * Nn + r]);
    o.z = 0.5f * (a.z + W[(c0 + 2) * Nn + r]);
    o.w = 0.5f * (a.w + W[(c0 + 3) * Nn + r]);
    *reinterpret_cast<float4*>(&wsym[r * Nn + c0]) = o;
}

// 512 threads = 8 waves (4x2); wave (wr,wc) owns rows [wr*64,+64) x cols
// [wc*128,+128) of C = F F^T.  acc[4][8] f32x4 = 128 accum regs; all acc
// indices compile-time (rule #20).  Staging: global_load_lds f32 -> linear
// 64KB scratch (zero VGPRs), then a convert pass writes the swizzled bf16
// tile; MFMA frag reads are single ds_read_b128, no in-loop cvt.
template <bool USE_WS>
__global__ __launch_bounds__(512, 2) void crf_mfma(
    const float* __restrict__ feats,   // [B, N, E]
    const float* __restrict__ logits,  // [B, N, 1]
    const float* __restrict__ W,       // [1, N, N] (raw; used if !USE_WS)
    const float* __restrict__ wsym,    // [N, N] precomputed 0.5*(W+W^T)
    float* __restrict__ out)           // [B, N, 1]
{
    const int b    = blockIdx.x;
    const int t    = threadIdx.x;
    const int wave = t >> 6;           // 0..7
    const int lane = t & 63;
    const int wr   = wave >> 1;        // 0..3 (64-row block)
    const int wc   = wave & 1;         // 0..1 (128-col block)
    const int lo   = lane & 15;        // C/D col = lo; A/B row = lo
    const int hi   = lane >> 4;        // C/D row = hi*4+reg; A/B k-base = hi*8

    __shared__ float fstage[Nn * TKF];          // 64 KB linear f32 chunk
    __shared__ unsigned char btile[Nn * 128];   // 32 KB swizzled bf16 tile
    __shared__ float invn[Nn];
    __shared__ float svec[Nn];
    __shared__ float uvec[Nn];
    __shared__ float lgv[Nn];
    __shared__ float part[4][Nn];

    f32x4 acc[4][8];
#pragma unroll
    for (int i = 0; i < 4; ++i)
#pragma unroll
        for (int j = 0; j < 8; ++j) acc[i][j] = (f32x4){0.f, 0.f, 0.f, 0.f};

    const float* Fb = feats + (size_t)b * Nn * Ee;

    // stage chunk ch -> fstage (linear): 8 x global_load_lds(16B)/wave, no VGPRs
    auto stage = [&](int ch) {
#pragma unroll
        for (int i = 0; i < 8; ++i) {
            const int r0s = wave * 32 + i * 4;        // wave-uniform row group
            const int row = r0s + (lane >> 4);        // 4 rows per issue
            const float* src = Fb + (size_t)row * Ee + ch * TKF + (lane & 15) * 4;
            __builtin_amdgcn_global_load_lds((glb_cv*)src,
                                             (lds_v*)(fstage + r0s * TKF), 16, 0, 0);
        }
    };

    // convert fstage (f32) -> btile (bf16, swizzled). 8 granules of 4 f32/thread.
    // Reads: lane-consecutive 16B (conflict-free). Writes: 8B at
    // gcol*8 ^ (row&7)<<4 -> 16 lanes cover a full 128B row span (conflict-free).
    auto convert = [&]() {
#pragma unroll
        for (int g = 0; g < 8; ++g) {
            const int m   = t + 512 * g;              // granule id (4 f32)
            const int row = m >> 4;
            const int gc  = m & 15;
            const float4 v = *reinterpret_cast<const float4*>(fstage + m * 4);
            ushort4 pk;
            pk.x = f2bf(v.x); pk.y = f2bf(v.y); pk.z = f2bf(v.z); pk.w = f2bf(v.w);
            *reinterpret_cast<ushort4*>(
                btile + row * 128 + ((gc * 8) ^ ((row & 7) << 4))) = pk;
        }
    };

    // ================= GEMM: C = F F^T =================
    stage(0);
    if (t < Nn) {
        const float u = logits[(size_t)b * Nn + t];
        uvec[t] = u;
        lgv[t]  = u;
    }
    __syncthreads();   // fstage(0) arrived (vmcnt drain at barrier)

    for (int ch = 0; ch < NCH; ++ch) {
        convert();
        __syncthreads();                 // btile ready; fstage consumed
        if (ch + 1 < NCH) stage(ch + 1); // refill fstage (in flight during MFMA)
#pragma unroll
        for (int ks = 0; ks < 2; ++ks) {
            bf16x8 af[4];
#pragma unroll
            for (int rb = 0; rb < 4; ++rb)
                af[rb] = ldfrag(btile, wr * 64 + rb * 16 + lo, ks, hi);
#pragma unroll
            for (int cg = 0; cg < 2; ++cg) {
                bf16x8 bfv[4];
#pragma unroll
                for (int cq = 0; cq < 4; ++cq)
                    bfv[cq] = ldfrag(btile, wc * 128 + (cg * 4 + cq) * 16 + lo, ks, hi);
#pragma unroll
                for (int rb = 0; rb < 4; ++rb)
#pragma unroll
                    for (int cq = 0; cq < 4; ++cq)
                        acc[rb][cg * 4 + cq] = __builtin_amdgcn_mfma_f32_16x16x32_bf16(
                            af[rb], bfv[cq], acc[rb][cg * 4 + cq], 0, 0, 0);
            }
        }
        __syncthreads();   // drains stage(ch+1) arrival + guards btile reuse
    }

    // ===== inverse norms from the diagonal (compile-time acc indices) =====
#pragma unroll
    for (int rb = 0; rb < 4; ++rb) {
        const int rowbase = wr * 64 + rb * 16;
#pragma unroll
        for (int cb = 0; cb < 8; ++cb) {
            const int colbase = wc * 128 + cb * 16;
            if (rowbase == colbase) {              // wave-uniform
#pragma unroll
                for (int r = 0; r < 4; ++r) {
                    if (hi * 4 + r == lo)
                        invn[rowbase + hi * 4 + r] = 1.0f / sqrtf(acc[rb][cb][r]);
                }
            }
        }
    }
    __syncthreads();

    // ===== P = C * invn_r * invn_c * Wsym[r][c], in registers =====
#pragma unroll
    for (int rb = 0; rb < 4; ++rb) {
        const int rbase = wr * 64 + rb * 16 + hi * 4;
        const float4 ir4 = *reinterpret_cast<const float4*>(&invn[rbase]);
        const float ir[4] = {ir4.x, ir4.y, ir4.z, ir4.w};
#pragma unroll
        for (int cb = 0; cb < 8; ++cb) {
            const int col = wc * 128 + cb * 16 + lo;
            const float ic = invn[col];
            if (USE_WS) {
#pragma unroll
                for (int r = 0; r < 4; ++r) {
                    const float ws = wsym[(rbase + r) * Nn + col];  // coalesced, L2-hot
                    acc[rb][cb][r] = acc[rb][cb][r] * ir[r] * ic * ws;
                }
            } else {
                const float4 wt = *reinterpret_cast<const float4*>(&W[col * Nn + rbase]);
                const float wtr[4] = {wt.x, wt.y, wt.z, wt.w};
#pragma unroll
                for (int r = 0; r < 4; ++r) {
                    const float ws = 0.5f * (W[(rbase + r) * Nn + col] + wtr[r]);
                    acc[rb][cb][r] = acc[rb][cb][r] * ir[r] * ic * ws;
                }
            }
        }
    }

    // ================= 10 mean-field iterations =================
    for (int itr = 0; itr < NITER; ++itr) {
        if (t < Nn) {
            const float x = lgv[t];
            svec[t] = 2.f / (1.f + __expf(-x)) - 1.f;
        }
        __syncthreads();

        float ep[8] = {0.f, 0.f, 0.f, 0.f, 0.f, 0.f, 0.f, 0.f};
#pragma unroll
        for (int rb = 0; rb < 4; ++rb) {
            const float4 s4 = *reinterpret_cast<const float4*>(
                &svec[wr * 64 + rb * 16 + hi * 4]);
#pragma unroll
            for (int cb = 0; cb < 8; ++cb)
                ep[cb] += acc[rb][cb][0] * s4.x + acc[rb][cb][1] * s4.y
                        + acc[rb][cb][2] * s4.z + acc[rb][cb][3] * s4.w;
        }
#pragma unroll
        for (int cb = 0; cb < 8; ++cb) {
            ep[cb] += __shfl_xor(ep[cb], 16);
            ep[cb] += __shfl_xor(ep[cb], 32);
        }
        if (lane < 16) {
#pragma unroll
            for (int cb = 0; cb < 8; ++cb)
                part[wr][wc * 128 + cb * 16 + lane] = ep[cb];
        }
        __syncthreads();
        if (t < Nn)
            lgv[t] = uvec[t] + part[0][t] + part[1][t] + part[2][t] + part[3][t];
    }

    if (t < Nn) out[(size_t)b * Nn + t] = lgv[t];
}

extern "C" void kernel_launch(void* const* d_in, const int* in_sizes, int n_in,
                              void* d_out, int out_size, void* d_ws, size_t ws_size,
                              hipStream_t stream) {
    const float* feats  = (const float*)d_in[0];
    const float* logits = (const float*)d_in[1];
    const float* W      = (const float*)d_in[2];
    float* out = (float*)d_out;

    if (ws_size >= (size_t)Nn * Nn * sizeof(float)) {
        float* wsym = (float*)d_ws;
        wsym_k<<<dim3(64), dim3(256), 0, stream>>>(W, wsym);
        crf_mfma<true><<<dim3(Bb), dim3(512), 0, stream>>>(feats, logits, W, wsym, out);
    } else {
        crf_mfma<false><<<dim3(Bb), dim3(512), 0, stream>>>(feats, logits, W, nullptr, out);
    }
}

// Round 8
// 45.528 us; speedup vs baseline: 3.7545x; 1.0690x over previous
//
#include <hip/hip_runtime.h>
#include <hip/hip_bf16.h>
#include <math.h>

// B=256, N=256, E=512, ITER=10
#define Bb   256
#define Nn   256
#define Ee   512
#define TKF  32             // k-elems per chunk (f32)
#define NCH  (Ee / TKF)     // 16 chunks
#define NITER 10

typedef __attribute__((ext_vector_type(8))) short bf16x8;   // MFMA A/B frag (4 VGPR)
typedef __attribute__((ext_vector_type(4))) float f32x4;    // MFMA C/D frag

typedef __attribute__((address_space(1))) const void glb_cv;
typedef __attribute__((address_space(3))) void lds_v;

// raw sync primitives: keep DMA loads in flight ACROSS barriers (T3/T4).
// __syncthreads() would emit s_waitcnt vmcnt(0) and drain the prefetch.
#define VMCNT(n) asm volatile("s_waitcnt vmcnt(" #n ")" ::: "memory")
#define LGKM0()  asm volatile("s_waitcnt lgkmcnt(0)" ::: "memory")

static __device__ __forceinline__ unsigned short f2bf(float f) {
    __hip_bfloat16 h = __float2bfloat16(f);     // RNE; pairs fuse to v_cvt_pk_bf16_f32
    return __builtin_bit_cast(unsigned short, h);
}

// bf16 tile: [256 rows][32 k], 64 B rows, XOR swizzle byte ^= (row&3)<<4.
// Frag read positions mod 128B: ((row&1)*64 + ((hi^(row&3))*16)) -> 8 distinct
// 16B slots x 8 lanes each = full 32-bank coverage (minimum cycles for b128).
static __device__ __forceinline__ bf16x8 ldfrag(const unsigned char* bt, int row, int hi) {
    const int byte = row * 64 + ((hi * 16) ^ ((row & 3) << 4));
    return *reinterpret_cast<const bf16x8*>(bt + byte);
}

// ---------- Wsym = 0.5*(W + W^T): direct version (proven round 7) ----------
__global__ __launch_bounds__(256) void wsym_k(const float* __restrict__ W,
                                              float* __restrict__ wsym) {
    const int idx = blockIdx.x * 256 + threadIdx.x;   // 0..16383
    const int r  = idx >> 6;                          // row 0..255
    const int c0 = (idx & 63) * 4;                    // col group
    const float4 a = *reinterpret_cast<const float4*>(&W[r * Nn + c0]);
    float4 o;
    o.x = 0.5f * (a.x + W[(c0 + 0) * Nn + r]);
    o.y = 0.5f * (a.y + W[(c0 + 1) * Nn + r]);
    o.z = 0.5f * (a.z + W[(c0 + 2) * Nn + r]);
    o.w = 0.5f * (a.w + W[(c0 + 3) * Nn + r]);
    *reinterpret_cast<float4*>(&wsym[r * Nn + c0]) = o;
}

// 512 threads = 8 waves (4x2); wave (wr,wc) owns rows [wr*64,+64) x cols
// [wc*128,+128) of C = F F^T.  acc[4][8] f32x4 = 128 accum regs; all acc
// indices compile-time (rule #20).
//
// K-loop schedule (2-deep DMA prefetch, counted vmcnt, raw barriers):
//   top:  vmcnt(4)  -- chunk ch arrived; chunk ch+1 stays in flight
//         barrier
//         convert fstage[ch&1] -> btile[ch&1]
//         lgkmcnt(0); barrier   -- cvt reads drained (fstage reusable),
//                                  btile writes visible
//         issue DMA(ch+2 -> fstage[ch&1])
//         MFMA over btile[ch&1]  (DMA streams underneath)
template <bool USE_WS>
__global__ __launch_bounds__(512, 2) void crf_mfma(
    const float* __restrict__ feats,   // [B, N, E]
    const float* __restrict__ logits,  // [B, N, 1]
    const float* __restrict__ W,       // [1, N, N] (raw; used if !USE_WS)
    const float* __restrict__ wsym,    // [N, N] precomputed 0.5*(W+W^T)
    float* __restrict__ out)           // [B, N, 1]
{
    const int b    = blockIdx.x;
    const int t    = threadIdx.x;
    const int wave = t >> 6;           // 0..7
    const int lane = t & 63;
    const int wr   = wave >> 1;        // 0..3 (64-row block)
    const int wc   = wave & 1;         // 0..1 (128-col block)
    const int lo   = lane & 15;        // C/D col = lo; A/B row = lo
    const int hi   = lane >> 4;        // C/D row = hi*4+reg; A/B k-base = hi*8

    __shared__ float fstage[2][Nn * TKF];        // 2 x 32 KB linear f32 chunk
    __shared__ unsigned char btile[2][Nn * 64];  // 2 x 16 KB swizzled bf16 tile
    __shared__ float invn[Nn];
    __shared__ float svec[Nn];
    __shared__ float uvec[Nn];
    __shared__ float lgv[Nn];
    __shared__ float part[4][Nn];

    f32x4 acc[4][8];
#pragma unroll
    for (int i = 0; i < 4; ++i)
#pragma unroll
        for (int j = 0; j < 8; ++j) acc[i][j] = (f32x4){0.f, 0.f, 0.f, 0.f};

    const float* Fb = feats + (size_t)b * Nn * Ee;

    // DMA chunk ch -> fstage[buf] (linear): 4 x global_load_lds(16B)/wave.
    // Each instr: 64 lanes x 16B = 1 KB = 8 rows x 128 B (coalesced).
    auto stage = [&](int ch, int buf) {
#pragma unroll
        for (int i = 0; i < 4; ++i) {
            const int gbase = wave * 4 + i;            // 1KB block id (0..31)
            const int row   = gbase * 8 + (lane >> 3); // per-lane row
            const float* src = Fb + (size_t)row * Ee + ch * TKF + (lane & 7) * 4;
            __builtin_amdgcn_global_load_lds((glb_cv*)src,
                                             (lds_v*)(&fstage[buf][gbase * 256]), 16, 0, 0);
        }
    };

    // convert fstage[buf] (f32) -> btile[buf] (bf16, swizzled).
    // Reads lane-consecutive 16B (conflict-free); writes 8B at
    // (gc*8)^((row&3)<<4) -> full row-span spread (conflict-free).
    auto convert = [&](int buf) {
#pragma unroll
        for (int g = 0; g < 4; ++g) {
            const int m   = t + 512 * g;              // granule id (4 f32)
            const int row = m >> 3;
            const int gc  = m & 7;
            const float4 v = *reinterpret_cast<const float4*>(&fstage[buf][m * 4]);
            ushort4 pk;
            pk.x = f2bf(v.x); pk.y = f2bf(v.y); pk.z = f2bf(v.z); pk.w = f2bf(v.w);
            *reinterpret_cast<ushort4*>(
                &btile[buf][row * 64 + ((gc * 8) ^ ((row & 3) << 4))]) = pk;
        }
    };

    auto mfma_step = [&](int buf) {
        const unsigned char* tb = &btile[buf][0];
        bf16x8 af[4];
#pragma unroll
        for (int rb = 0; rb < 4; ++rb)
            af[rb] = ldfrag(tb, wr * 64 + rb * 16 + lo, hi);
#pragma unroll
        for (int cg = 0; cg < 2; ++cg) {
            bf16x8 bfv[4];
#pragma unroll
            for (int cq = 0; cq < 4; ++cq)
                bfv[cq] = ldfrag(tb, wc * 128 + (cg * 4 + cq) * 16 + lo, hi);
#pragma unroll
            for (int rb = 0; rb < 4; ++rb)
#pragma unroll
                for (int cq = 0; cq < 4; ++cq)
                    acc[rb][cg * 4 + cq] = __builtin_amdgcn_mfma_f32_16x16x32_bf16(
                        af[rb], bfv[cq], acc[rb][cg * 4 + cq], 0, 0, 0);
        }
    };

    // ---- prologue: logits load FIRST (oldest in vmcnt queue), then 2 DMAs ----
    float uval = 0.f;
    if (t < Nn) uval = logits[(size_t)b * Nn + t];
    stage(0, 0);
    stage(1, 1);
    if (t < Nn) {              // compiler waits only the logits load (vmcnt(8))
        uvec[t] = uval;
        lgv[t]  = uval;
    }

    // ================= GEMM: C = F F^T =================
#pragma unroll 2
    for (int ch = 0; ch < NCH; ++ch) {
        if (ch + 1 < NCH) { VMCNT(4); } else { VMCNT(0); }
        __builtin_amdgcn_s_barrier();          // all waves: chunk ch staged
        convert(ch & 1);
        LGKM0();                               // cvt reads+writes drained
        __builtin_amdgcn_s_barrier();          // btile visible; fstage reusable
        if (ch + 2 < NCH) stage(ch + 2, ch & 1);
        mfma_step(ch & 1);                     // DMA streams under MFMA
    }

    // ===== inverse norms from the diagonal (compile-time acc indices) =====
#pragma unroll
    for (int rb = 0; rb < 4; ++rb) {
        const int rowbase = wr * 64 + rb * 16;
#pragma unroll
        for (int cb = 0; cb < 8; ++cb) {
            const int colbase = wc * 128 + cb * 16;
            if (rowbase == colbase) {              // wave-uniform
#pragma unroll
                for (int r = 0; r < 4; ++r) {
                    if (hi * 4 + r == lo)
                        invn[rowbase + hi * 4 + r] = 1.0f / sqrtf(acc[rb][cb][r]);
                }
            }
        }
    }
    __syncthreads();

    // ===== P = C * invn_r * invn_c * Wsym[r][c], in registers =====
#pragma unroll
    for (int rb = 0; rb < 4; ++rb) {
        const int rbase = wr * 64 + rb * 16 + hi * 4;
        const float4 ir4 = *reinterpret_cast<const float4*>(&invn[rbase]);
        const float ir[4] = {ir4.x, ir4.y, ir4.z, ir4.w};
#pragma unroll
        for (int cb = 0; cb < 8; ++cb) {
            const int col = wc * 128 + cb * 16 + lo;
            const float ic = invn[col];
            if (USE_WS) {
#pragma unroll
                for (int r = 0; r < 4; ++r) {
                    const float ws = wsym[(rbase + r) * Nn + col];  // coalesced, L2-hot
                    acc[rb][cb][r] = acc[rb][cb][r] * ir[r] * ic * ws;
                }
            } else {
                const float4 wt = *reinterpret_cast<const float4*>(&W[col * Nn + rbase]);
                const float wtr[4] = {wt.x, wt.y, wt.z, wt.w};
#pragma unroll
                for (int r = 0; r < 4; ++r) {
                    const float ws = 0.5f * (W[(rbase + r) * Nn + col] + wtr[r]);
                    acc[rb][cb][r] = acc[rb][cb][r] * ir[r] * ic * ws;
                }
            }
        }
    }

    // ================= 10 mean-field iterations =================
    // P symmetric -> e[col] = sum_row P[row][col]*s[row]: in-lane over 16 rows,
    // butterfly over hi-groups, LDS partials over the 4 wr row-blocks.
    for (int itr = 0; itr < NITER; ++itr) {
        if (t < Nn) {
            const float x = lgv[t];
            svec[t] = 2.f / (1.f + __expf(-x)) - 1.f;
        }
        __syncthreads();

        float ep[8] = {0.f, 0.f, 0.f, 0.f, 0.f, 0.f, 0.f, 0.f};
#pragma unroll
        for (int rb = 0; rb < 4; ++rb) {
            const float4 s4 = *reinterpret_cast<const float4*>(
                &svec[wr * 64 + rb * 16 + hi * 4]);
#pragma unroll
            for (int cb = 0; cb < 8; ++cb)
                ep[cb] += acc[rb][cb][0] * s4.x + acc[rb][cb][1] * s4.y
                        + acc[rb][cb][2] * s4.z + acc[rb][cb][3] * s4.w;
        }
#pragma unroll
        for (int cb = 0; cb < 8; ++cb) {
            ep[cb] += __shfl_xor(ep[cb], 16);
            ep[cb] += __shfl_xor(ep[cb], 32);
        }
        if (lane < 16) {
#pragma unroll
            for (int cb = 0; cb < 8; ++cb)
                part[wr][wc * 128 + cb * 16 + lane] = ep[cb];
        }
        __syncthreads();
        if (t < Nn)
            lgv[t] = uvec[t] + part[0][t] + part[1][t] + part[2][t] + part[3][t];
    }

    if (t < Nn) out[(size_t)b * Nn + t] = lgv[t];
}

extern "C" void kernel_launch(void* const* d_in, const int* in_sizes, int n_in,
                              void* d_out, int out_size, void* d_ws, size_t ws_size,
                              hipStream_t stream) {
    const float* feats  = (const float*)d_in[0];
    const float* logits = (const float*)d_in[1];
    const float* W      = (const float*)d_in[2];
    float* out = (float*)d_out;

    if (ws_size >= (size_t)Nn * Nn * sizeof(float)) {
        float* wsym = (float*)d_ws;
        wsym_k<<<dim3(64), dim3(256), 0, stream>>>(W, wsym);
        crf_mfma<true><<<dim3(Bb), dim3(512), 0, stream>>>(feats, logits, W, wsym, out);
    } else {
        crf_mfma<false><<<dim3(Bb), dim3(512), 0, stream>>>(feats, logits, W, nullptr, out);
    }
}